// Round 13
// baseline (372.266 us; speedup 1.0000x reference)
//
#include <hip/hip_runtime.h>
#include <hip/hip_bf16.h>

typedef __bf16 bf16x8 __attribute__((ext_vector_type(8)));
typedef float f32x4 __attribute__((ext_vector_type(4)));

__device__ __forceinline__ unsigned short f2bf(float f) {
  union { float f; unsigned u; } x; x.f = f;
  unsigned r = x.u + 0x7fffu + ((x.u >> 16) & 1u);
  return (unsigned short)(r >> 16);
}
__device__ __forceinline__ float bf2f(unsigned short u) {
  union { unsigned u; float f; } x; x.u = (unsigned)u << 16;
  return x.f;
}
__device__ __forceinline__ unsigned short f2h(float f) {
  union { _Float16 h; unsigned short u; } x; x.h = (_Float16)f;
  return x.u;
}
__device__ __forceinline__ float h2f(unsigned short u) {
  union { _Float16 h; unsigned short u; } x; x.u = u;
  return (float)x.h;
}

__device__ __forceinline__ void async_ld16(const void* g, void* l) {
  __builtin_amdgcn_global_load_lds(
      (__attribute__((address_space(1))) void*)const_cast<void*>(g),
      (__attribute__((address_space(3))) void*)l, 16, 0, 0);
}

#define SB __builtin_amdgcn_sched_barrier(0)

#define EPI_F32    0
#define EPI_BF     1
#define EPI_RELUBF 2
#define EPI_F16    3

// ---- r7 GEMM (best measured): 256x256, 4-phase K-split, 2 gates/K-tile ----
// Used for attnV + FFN1 + FFN2. Ledger/swizzle verified rounds 7-12.
__global__ __launch_bounds__(512, 2) void gemm_bt(
    const unsigned short* __restrict__ A,   // [nb][M][K] bf16
    const unsigned short* __restrict__ Bt,  // [nb][N][K] bf16
    int M, int N, int K, int nbatch,
    long sA, long sB, long sC,
    float scale, int mode, void* __restrict__ outp)
{
  __shared__ unsigned short lds[65536];  // 128 KB
  const int t = threadIdx.x;
  const int w = t >> 6, l = t & 63;
  const int lr = l & 15, lg = l >> 4;
  const int wr = w >> 2, wc = w & 3;           // 2 M-waves x 4 N-waves
  const int ntn = N >> 8;
  const int tiles = (M >> 8) * ntn;
  const int chunk = (tiles * nbatch) >> 3;
  const int bid = blockIdx.x;
  const int wg = (bid & 7) * chunk + (bid >> 3);
  const int batch = wg / tiles;
  const int rem = wg - batch * tiles;
  const int row0 = (rem / ntn) << 8;
  const int col0 = (rem % ntn) << 8;

  const unsigned short* Ab  = A  + (long)batch * sA;
  const unsigned short* Btb = Bt + (long)batch * sB;

  const int ks = ((lg ^ ((lr >> 1) & 3)) << 3);
  const int srow = w * 16 + (l >> 2);
  const int kgo  = (((l & 3) ^ ((l >> 3) & 3)) << 3);
  const long aoff0 = (long)(row0 + srow) * K + kgo;
  const long boff0 = (long)(col0 + srow) * K + kgo;
  const long off128 = (long)K << 7;

  const int NT = K >> 6;

#define STAGEP(partE, base, kcol)                                      \
  { async_ld16((base) + (kcol),          &lds[(partE) + t * 8]);       \
    async_ld16((base) + off128 + (kcol), &lds[(partE) + 4096 + t * 8]); }

  f32x4 acc[8][4];
#pragma unroll
  for (int m = 0; m < 8; ++m)
#pragma unroll
    for (int n = 0; n < 4; ++n) acc[m][n] = (f32x4){0.f, 0.f, 0.f, 0.f};

  STAGEP(0,     Btb + boff0, 0);
  STAGEP(8192,  Ab + aoff0,  0);
  STAGEP(16384, Btb + boff0, 32);
  STAGEP(24576, Ab + aoff0,  32);
  SB;

  for (int tt = 0; tt < NT; ++tt) {
    const int bufe  = (tt & 1) << 15;
    const int nbufe = ((tt + 1) & 1) << 15;
    const bool st = (tt + 1) < NT;
    const int kn = (tt + 1) << 6;

#pragma unroll
    for (int kh = 0; kh < 2; ++kh) {
      if (kh == 0 || st) { asm volatile("s_waitcnt vmcnt(4)" ::: "memory"); }
      else               { asm volatile("s_waitcnt vmcnt(0)" ::: "memory"); }
      SB;
      __builtin_amdgcn_s_barrier();
      SB;

      const int pB = bufe + kh * 16384;
      const int pA = pB + 8192;

      bf16x8 bfr[4];
#pragma unroll
      for (int nf = 0; nf < 4; ++nf) {
        int rb = wc * 64 + nf * 16 + lr;
        bfr[nf] = *(const bf16x8*)&lds[pB + rb * 32 + ks];
      }
      {
        bf16x8 af[4];
#pragma unroll
        for (int i = 0; i < 4; ++i) {
          int ra = wr * 128 + i * 16 + lr;
          af[i] = *(const bf16x8*)&lds[pA + ra * 32 + ks];
        }
        if (st) STAGEP(nbufe + kh * 16384, Btb + boff0, kn + kh * 32);
        __builtin_amdgcn_s_setprio(1);
#pragma unroll
        for (int i = 0; i < 4; ++i)
#pragma unroll
          for (int nf = 0; nf < 4; ++nf)
            acc[i][nf] = __builtin_amdgcn_mfma_f32_16x16x32_bf16(af[i], bfr[nf], acc[i][nf], 0, 0, 0);
        __builtin_amdgcn_s_setprio(0);
      }
      {
        bf16x8 af[4];
#pragma unroll
        for (int i = 0; i < 4; ++i) {
          int ra = wr * 128 + 64 + i * 16 + lr;
          af[i] = *(const bf16x8*)&lds[pA + ra * 32 + ks];
        }
        if (st) STAGEP(nbufe + kh * 16384 + 8192, Ab + aoff0, kn + kh * 32);
        __builtin_amdgcn_s_setprio(1);
#pragma unroll
        for (int i = 0; i < 4; ++i)
#pragma unroll
          for (int nf = 0; nf < 4; ++nf)
            acc[4 + i][nf] = __builtin_amdgcn_mfma_f32_16x16x32_bf16(af[i], bfr[nf], acc[4 + i][nf], 0, 0, 0);
        __builtin_amdgcn_s_setprio(0);
      }
      SB;
    }
  }

  float* outF = (float*)outp;
  unsigned short* outH = (unsigned short*)outp;
  const size_t cb = (size_t)batch * (size_t)sC;
#pragma unroll
  for (int mf = 0; mf < 8; ++mf) {
    int rbase = row0 + wr * 128 + mf * 16 + lg * 4;
#pragma unroll
    for (int nf = 0; nf < 4; ++nf) {
      int c = col0 + wc * 64 + nf * 16 + lr;
      f32x4 v = acc[mf][nf];
#pragma unroll
      for (int q = 0; q < 4; ++q) {
        size_t idx = cb + (size_t)(rbase + q) * N + c;
        float val = v[q] * scale;
        if (mode == EPI_F32)         outF[idx] = val;
        else if (mode == EPI_BF)     outH[idx] = f2bf(val);
        else if (mode == EPI_RELUBF) outH[idx] = f2bf(fmaxf(val, 0.f));
        else                         outH[idx] = f2h(val);
      }
    }
  }
#undef STAGEP
}

// ---- g1_fused: x = seq(f32) @ embT^T * scale -> bf16 (r11 version) ----
__global__ __launch_bounds__(512, 2) void g1_fused(
    const float* __restrict__ A,            // [16384][768] f32
    const unsigned short* __restrict__ Bt,  // [1024][768] bf16
    float scale, unsigned short* __restrict__ outB)
{
  __shared__ unsigned short lds[65536];
  const int t = threadIdx.x;
  const int w = t >> 6, l = t & 63;
  const int lr = l & 15, lg = l >> 4;
  const int wr = w >> 2, wc = w & 3;
  const int K = 768;
  const int bid = blockIdx.x;
  const int wg = (bid & 7) * 32 + (bid >> 3);   // 256 tiles (64x4)
  const int row0 = (wg >> 2) << 8;
  const int col0 = (wg & 3) << 8;

  const int ks = ((lg ^ ((lr >> 1) & 3)) << 3);
  const int srow = w * 16 + (l >> 2);
  const int kgo  = (((l & 3) ^ ((l >> 3) & 3)) << 3);
  const long ar0 = (long)(row0 + srow) * K + kgo;
  const long ar1 = ar0 + (long)128 * K;
  const long boff0 = (long)(col0 + srow) * K + kgo;
  const long off128 = (long)K << 7;
  const int NT = 12;

#define STAGEB(partE, kcol)                                              \
  { async_ld16(Bt + boff0 + (kcol),          &lds[(partE) + t * 8]);     \
    async_ld16(Bt + boff0 + off128 + (kcol), &lds[(partE) + 4096 + t * 8]); }
#define WRA(partE, q0, q1, q2, q3)                                       \
  { uint4 pk;                                                            \
    pk.x = (unsigned)f2bf(q0.x) | ((unsigned)f2bf(q0.y) << 16);          \
    pk.y = (unsigned)f2bf(q0.z) | ((unsigned)f2bf(q0.w) << 16);          \
    pk.z = (unsigned)f2bf(q1.x) | ((unsigned)f2bf(q1.y) << 16);          \
    pk.w = (unsigned)f2bf(q1.z) | ((unsigned)f2bf(q1.w) << 16);          \
    *(uint4*)&lds[(partE) + t * 8] = pk;                                 \
    pk.x = (unsigned)f2bf(q2.x) | ((unsigned)f2bf(q2.y) << 16);          \
    pk.y = (unsigned)f2bf(q2.z) | ((unsigned)f2bf(q2.w) << 16);          \
    pk.z = (unsigned)f2bf(q3.x) | ((unsigned)f2bf(q3.y) << 16);          \
    pk.w = (unsigned)f2bf(q3.z) | ((unsigned)f2bf(q3.w) << 16);          \
    *(uint4*)&lds[(partE) + 4096 + t * 8] = pk; }

  f32x4 acc[8][4];
#pragma unroll
  for (int m = 0; m < 8; ++m)
#pragma unroll
    for (int n = 0; n < 4; ++n) acc[m][n] = (f32x4){0.f, 0.f, 0.f, 0.f};

  float4 ap0, ap1, ap2, ap3, ap4, ap5, ap6, ap7;
  ap0 = *(const float4*)&A[ar0];      ap1 = *(const float4*)&A[ar0 + 4];
  ap2 = *(const float4*)&A[ar1];      ap3 = *(const float4*)&A[ar1 + 4];
  ap4 = *(const float4*)&A[ar0 + 32]; ap5 = *(const float4*)&A[ar0 + 36];
  ap6 = *(const float4*)&A[ar1 + 32]; ap7 = *(const float4*)&A[ar1 + 36];
  STAGEB(0, 0);
  STAGEB(16384, 32);
  WRA(8192,  ap0, ap1, ap2, ap3);
  WRA(24576, ap4, ap5, ap6, ap7);
  SB;

  for (int tt = 0; tt < NT; ++tt) {
    const int bufe  = (tt & 1) << 15;
    const int nbufe = ((tt + 1) & 1) << 15;
    const bool st = (tt + 1) < NT;
    const int kn = (tt + 1) << 6;

#pragma unroll
    for (int kh = 0; kh < 2; ++kh) {
      if (kh == 0)  { asm volatile("s_waitcnt vmcnt(2) lgkmcnt(0)" ::: "memory"); }
      else if (st)  { asm volatile("s_waitcnt vmcnt(10) lgkmcnt(0)" ::: "memory"); }
      else          { asm volatile("s_waitcnt vmcnt(0) lgkmcnt(0)" ::: "memory"); }
      SB;
      __builtin_amdgcn_s_barrier();
      SB;

      const int pB = bufe + kh * 16384;
      const int pA = pB + 8192;

      bf16x8 bfr[4];
#pragma unroll
      for (int nf = 0; nf < 4; ++nf) {
        int rb = wc * 64 + nf * 16 + lr;
        bfr[nf] = *(const bf16x8*)&lds[pB + rb * 32 + ks];
      }
      {
        bf16x8 af[4];
#pragma unroll
        for (int i = 0; i < 4; ++i) {
          int ra = wr * 128 + i * 16 + lr;
          af[i] = *(const bf16x8*)&lds[pA + ra * 32 + ks];
        }
        if (kh == 0 && st) {
          ap0 = *(const float4*)&A[ar0 + kn];      ap1 = *(const float4*)&A[ar0 + kn + 4];
          ap2 = *(const float4*)&A[ar1 + kn];      ap3 = *(const float4*)&A[ar1 + kn + 4];
          ap4 = *(const float4*)&A[ar0 + kn + 32]; ap5 = *(const float4*)&A[ar0 + kn + 36];
          ap6 = *(const float4*)&A[ar1 + kn + 32]; ap7 = *(const float4*)&A[ar1 + kn + 36];
          STAGEB(nbufe + 0, kn);
        }
        __builtin_amdgcn_s_setprio(1);
#pragma unroll
        for (int i = 0; i < 4; ++i)
#pragma unroll
          for (int nf = 0; nf < 4; ++nf)
            acc[i][nf] = __builtin_amdgcn_mfma_f32_16x16x32_bf16(af[i], bfr[nf], acc[i][nf], 0, 0, 0);
        __builtin_amdgcn_s_setprio(0);
      }
      {
        bf16x8 af[4];
#pragma unroll
        for (int i = 0; i < 4; ++i) {
          int ra = wr * 128 + 64 + i * 16 + lr;
          af[i] = *(const bf16x8*)&lds[pA + ra * 32 + ks];
        }
        if (kh == 1 && st) STAGEB(nbufe + 16384, kn + 32);
        __builtin_amdgcn_s_setprio(1);
#pragma unroll
        for (int i = 0; i < 4; ++i)
#pragma unroll
          for (int nf = 0; nf < 4; ++nf)
            acc[4 + i][nf] = __builtin_amdgcn_mfma_f32_16x16x32_bf16(af[i], bfr[nf], acc[4 + i][nf], 0, 0, 0);
        __builtin_amdgcn_s_setprio(0);
        if (kh == 1 && st) {
          WRA(nbufe + 8192,  ap0, ap1, ap2, ap3);
          WRA(nbufe + 24576, ap4, ap5, ap6, ap7);
        }
      }
      SB;
    }
  }

#pragma unroll
  for (int mf = 0; mf < 8; ++mf) {
    int rbase = row0 + wr * 128 + mf * 16 + lg * 4;
#pragma unroll
    for (int nf = 0; nf < 4; ++nf) {
      int c = col0 + wc * 64 + nf * 16 + lr;
      f32x4 v = acc[mf][nf];
#pragma unroll
      for (int q = 0; q < 4; ++q)
        outB[(size_t)(rbase + q) * 1024 + c] = f2bf(v[q] * scale);
    }
  }
#undef STAGEB
#undef WRA
}

// ---- gram_tr: blocks [0,576): triangular 128x256 gram -> f16 (r11 version).
//      blocks [576,1088): xT[b] = x[b]^T (32 tiles of 32x32 each) — fills the
//      gram tail (576 = 2.25 rounds at 1 block/CU; 192 CUs idle in round 3).
//      Both parts only READ X and write disjoint outputs -> order-independent.
__global__ __launch_bounds__(512, 2) void gram_tr(
    const unsigned short* __restrict__ X,   // [8][2048][1024] bf16
    unsigned short* __restrict__ outH,      // [8][2048][2048] f16
    unsigned short* __restrict__ xT)        // [8][1024][2048] bf16
{
  __shared__ unsigned short lds[49152];  // 96 KB
  const int t = threadIdx.x;
  const int bid = blockIdx.x;

  if (bid >= 576) {
    // ---------- transpose part ----------
    unsigned short (*tl)[33] = (unsigned short(*)[33])lds;
    const int tid = bid - 576;                // 0..511
    const int tx = t & 31, trow = (t >> 5);   // 16 row-threads
    for (int i = 0; i < 32; ++i) {
      const int tix = tid * 32 + i;           // 0..16383
      const int b  = tix >> 11;               // 2048 tiles/batch
      const int r5 = (tix >> 5) & 63;         // row-tile 0..63
      const int c5 = tix & 31;                // col-tile 0..31
      const size_t zb = (size_t)b * 2048 * 1024;
      const int r0 = r5 << 5, c0 = c5 << 5;
      __syncthreads();
      for (int rr = trow; rr < 32; rr += 16)
        tl[rr][tx] = X[zb + (size_t)(r0 + rr) * 1024 + c0 + tx];
      __syncthreads();
      for (int rr = trow; rr < 32; rr += 16)
        xT[zb + (size_t)(c0 + rr) * 2048 + r0 + tx] = tl[tx][rr];
    }
    return;
  }

  // ---------- gram part (r11 gram_sym2, unchanged) ----------
  const int w = t >> 6, l = t & 63;
  const int lr = l & 15, lg = l >> 4;
  const int wr = w >> 2, wc = w & 3;     // 2 M-waves x 4 N-waves
  const int wg = (bid & 7) * 72 + (bid >> 3);
  const int batch = wg / 72;
  int f = wg - batch * 72;
  int bi = 0;
  while (f >= 8 - (bi >> 1)) { f -= 8 - (bi >> 1); ++bi; }
  const int bj = (bi >> 1) + f;
  const int row0 = bi << 7;              // 128-row tile
  const int col0 = bj << 8;              // 256-col tile

  const unsigned short* Xb = X + (long)batch * 2048 * 1024;

  const int ks = ((lg ^ ((lr >> 1) & 3)) << 3);
  const int srow = w * 16 + (l >> 2);
  const int kgoB = (((l & 3) ^ ((l >> 3) & 3)) << 3);
  const long boff0 = (long)(col0 + srow) * 1024 + kgoB;
  const long off128 = 1024L << 7;
  const long arow = (long)(row0 + (t >> 2)) * 1024 + (((t & 3) ^ ((t >> 3) & 3)) << 3);

#define STAGEB2(partE, kcol)                                              \
  { async_ld16(Xb + boff0 + (kcol),          &lds[(partE) + t * 8]);      \
    async_ld16(Xb + boff0 + off128 + (kcol), &lds[(partE) + 4096 + t * 8]); }
#define STAGEA2(partE, kcol)                                              \
  { async_ld16(Xb + arow + (kcol), &lds[(partE) + t * 8]); }

  f32x4 acc[4][4];
#pragma unroll
  for (int m = 0; m < 4; ++m)
#pragma unroll
    for (int n = 0; n < 4; ++n) acc[m][n] = (f32x4){0.f, 0.f, 0.f, 0.f};

  STAGEB2(0, 0);
  STAGEA2(8192, 0);
  STAGEB2(12288, 32);
  STAGEA2(20480, 32);
  SB;

  for (int tt = 0; tt < 16; ++tt) {
    const int bufe  = (tt & 1) * 24576;
    const int nbufe = ((tt + 1) & 1) * 24576;
    const bool st = (tt + 1) < 16;
    const int kn = (tt + 1) << 6;

#pragma unroll
    for (int kh = 0; kh < 2; ++kh) {
      if (kh == 0 || st) { asm volatile("s_waitcnt vmcnt(3)" ::: "memory"); }
      else               { asm volatile("s_waitcnt vmcnt(0)" ::: "memory"); }
      SB;
      __builtin_amdgcn_s_barrier();
      SB;

      const int pB = bufe + kh * 12288;
      const int pA = pB + 8192;

      bf16x8 bfr[4];
#pragma unroll
      for (int nf = 0; nf < 4; ++nf) {
        int rb = wc * 64 + nf * 16 + lr;
        bfr[nf] = *(const bf16x8*)&lds[pB + rb * 32 + ks];
      }
#pragma unroll
      for (int mh = 0; mh < 2; ++mh) {
        bf16x8 af[2];
#pragma unroll
        for (int i = 0; i < 2; ++i) {
          int ra = wr * 64 + mh * 32 + i * 16 + lr;
          af[i] = *(const bf16x8*)&lds[pA + ra * 32 + ks];
        }
        if (st) {
          if (mh == 0) { if (kh == 0) STAGEB2(nbufe + 0, kn) else STAGEB2(nbufe + 12288, kn + 32) }
          else         { if (kh == 0) STAGEA2(nbufe + 8192, kn) else STAGEA2(nbufe + 20480, kn + 32) }
        }
        __builtin_amdgcn_s_setprio(1);
#pragma unroll
        for (int i = 0; i < 2; ++i)
#pragma unroll
          for (int nf = 0; nf < 4; ++nf)
            acc[mh * 2 + i][nf] = __builtin_amdgcn_mfma_f32_16x16x32_bf16(af[i], bfr[nf], acc[mh * 2 + i][nf], 0, 0, 0);
        __builtin_amdgcn_s_setprio(0);
      }
      SB;
    }
  }

  unsigned short* ob = outH + (size_t)batch * 2048 * 2048;
  const float scale = 1.0f / 1024.0f;
#pragma unroll
  for (int am = 0; am < 4; ++am) {
    int rbase = row0 + wr * 64 + (am >> 1) * 32 + (am & 1) * 16 + lg * 4;
#pragma unroll
    for (int nf = 0; nf < 4; ++nf) {
      int c = col0 + wc * 64 + nf * 16 + lr;
      f32x4 v = acc[am][nf];
      unsigned short h0 = f2h(v[0] * scale), h1 = f2h(v[1] * scale);
      unsigned short h2 = f2h(v[2] * scale), h3 = f2h(v[3] * scale);
      ob[(size_t)(rbase + 0) * 2048 + c] = h0;
      ob[(size_t)(rbase + 1) * 2048 + c] = h1;
      ob[(size_t)(rbase + 2) * 2048 + c] = h2;
      ob[(size_t)(rbase + 3) * 2048 + c] = h3;
      ushort4 m4 = {h0, h1, h2, h3};
      *(ushort4*)&ob[(size_t)c * 2048 + rbase] = m4;
    }
  }
#undef STAGEB2
#undef STAGEA2
}

// ---------------- elementwise / reduction kernels ----------------

__device__ __forceinline__ float wave_sum(float v) {
#pragma unroll
  for (int o = 32; o; o >>= 1) v += __shfl_xor(v, o, 64);
  return v;
}
__device__ __forceinline__ float wave_max(float v) {
#pragma unroll
  for (int o = 32; o; o >>= 1) v = fmaxf(v, __shfl_xor(v, o, 64));
  return v;
}

// all three weight transposes in one launch: z=0 emb[768][1024], z=1 W1, z=2 W2
__global__ __launch_bounds__(256) void transpose_cast3(
    const float* __restrict__ emb, const float* __restrict__ W1,
    const float* __restrict__ W2, unsigned short* __restrict__ embT,
    unsigned short* __restrict__ W1T, unsigned short* __restrict__ W2T) {
  __shared__ float tile[32][33];
  const int z = blockIdx.z;
  const float* in = (z == 0) ? emb : (z == 1) ? W1 : W2;
  unsigned short* out = (z == 0) ? embT : (z == 1) ? W1T : W2T;
  const int R = (z == 0) ? 768 : 1024;
  int c0 = blockIdx.x * 32, r0 = blockIdx.y * 32;
  if (r0 >= R) return;
  int tx = threadIdx.x, ty = threadIdx.y;  // block (32,8)
  for (int i = ty; i < 32; i += 8) tile[i][tx] = in[(size_t)(r0 + i) * 1024 + c0 + tx];
  __syncthreads();
  for (int i = ty; i < 32; i += 8) out[(size_t)(c0 + i) * R + r0 + tx] = f2bf(tile[tx][i]);
}

__global__ __launch_bounds__(256) void softmax_rows(const unsigned short* __restrict__ g,
                                                    unsigned short* __restrict__ wout) {
  __shared__ float red[4];
  int row = blockIdx.x, t = threadIdx.x;
  const unsigned short* gr = g + ((size_t)row << 11) + t * 8;
  ushort4 ua = *(const ushort4*)gr;
  ushort4 ub = *(const ushort4*)(gr + 4);
  float a0 = h2f(ua.x), a1 = h2f(ua.y), a2 = h2f(ua.z), a3 = h2f(ua.w);
  float b0 = h2f(ub.x), b1 = h2f(ub.y), b2 = h2f(ub.z), b3 = h2f(ub.w);
  float mx = fmaxf(fmaxf(fmaxf(a0, a1), fmaxf(a2, a3)),
                   fmaxf(fmaxf(b0, b1), fmaxf(b2, b3)));
  mx = wave_max(mx);
  if ((t & 63) == 0) red[t >> 6] = mx;
  __syncthreads();
  mx = fmaxf(fmaxf(red[0], red[1]), fmaxf(red[2], red[3]));
  float e0 = __expf(a0 - mx), e1 = __expf(a1 - mx), e2 = __expf(a2 - mx), e3 = __expf(a3 - mx);
  float e4 = __expf(b0 - mx), e5 = __expf(b1 - mx), e6 = __expf(b2 - mx), e7 = __expf(b3 - mx);
  float s = ((e0 + e1) + (e2 + e3)) + ((e4 + e5) + (e6 + e7));
  s = wave_sum(s);
  __syncthreads();
  if ((t & 63) == 0) red[t >> 6] = s;
  __syncthreads();
  s = (red[0] + red[1]) + (red[2] + red[3]);
  float inv = 1.0f / s;
  ushort4 o0, o1;
  o0.x = f2bf(e0 * inv); o0.y = f2bf(e1 * inv); o0.z = f2bf(e2 * inv); o0.w = f2bf(e3 * inv);
  o1.x = f2bf(e4 * inv); o1.y = f2bf(e5 * inv); o1.z = f2bf(e6 * inv); o1.w = f2bf(e7 * inv);
  size_t base = ((size_t)row << 11) + t * 8;
  *(ushort4*)&wout[base] = o0;
  *(ushort4*)&wout[base + 4] = o1;
}

// post = LN(x_b + attn_b), both bf16
__global__ __launch_bounds__(256) void ln_residual_bb(const unsigned short* __restrict__ xb,
                                                      const unsigned short* __restrict__ ab,
                                                      unsigned short* __restrict__ outB) {
  __shared__ float red[4];
  int row = blockIdx.x, t = threadIdx.x;
  size_t base = ((size_t)row << 10) + t * 4;
  ushort4 ua = *(const ushort4*)&xb[base];
  ushort4 ub = *(const ushort4*)&ab[base];
  float4 v = {bf2f(ua.x) + bf2f(ub.x), bf2f(ua.y) + bf2f(ub.y),
              bf2f(ua.z) + bf2f(ub.z), bf2f(ua.w) + bf2f(ub.w)};
  float s = (v.x + v.y) + (v.z + v.w);
  float ss = (v.x * v.x + v.y * v.y) + (v.z * v.z + v.w * v.w);
  s = wave_sum(s);
  if ((t & 63) == 0) red[t >> 6] = s;
  __syncthreads();
  s = (red[0] + red[1]) + (red[2] + red[3]);
  ss = wave_sum(ss);
  __syncthreads();
  if ((t & 63) == 0) red[t >> 6] = ss;
  __syncthreads();
  ss = (red[0] + red[1]) + (red[2] + red[3]);
  float mean = s * (1.0f / 1024.0f);
  float var = (ss - s * mean) * (1.0f / 1023.0f);
  float rstd = rsqrtf(var);
  ushort4 ob;
  ob.x = f2bf((v.x - mean) * rstd); ob.y = f2bf((v.y - mean) * rstd);
  ob.z = f2bf((v.z - mean) * rstd); ob.w = f2bf((v.w - mean) * rstd);
  *(ushort4*)&outB[base] = ob;
}

__global__ __launch_bounds__(256) void ln_residual_dot(const unsigned short* __restrict__ h2,
                                                       const unsigned short* __restrict__ post,
                                                       const float* __restrict__ readout,
                                                       float* __restrict__ rowdot) {
  __shared__ float red[4];
  int row = blockIdx.x, t = threadIdx.x;
  size_t base = ((size_t)row << 10) + t * 4;
  ushort4 ua = *(const ushort4*)&h2[base];
  ushort4 ub = *(const ushort4*)&post[base];
  float4 v = {bf2f(ua.x) + bf2f(ub.x), bf2f(ua.y) + bf2f(ub.y),
              bf2f(ua.z) + bf2f(ub.z), bf2f(ua.w) + bf2f(ub.w)};
  float s = (v.x + v.y) + (v.z + v.w);
  float ss = (v.x * v.x + v.y * v.y) + (v.z * v.z + v.w * v.w);
  s = wave_sum(s);
  if ((t & 63) == 0) red[t >> 6] = s;
  __syncthreads();
  s = (red[0] + red[1]) + (red[2] + red[3]);
  ss = wave_sum(ss);
  __syncthreads();
  if ((t & 63) == 0) red[t >> 6] = ss;
  __syncthreads();
  ss = (red[0] + red[1]) + (red[2] + red[3]);
  float mean = s * (1.0f / 1024.0f);
  float var = (ss - s * mean) * (1.0f / 1023.0f);
  float rstd = rsqrtf(var);
  float4 r = *(const float4*)&readout[t * 4];
  float dot = (v.x - mean) * rstd * r.x + (v.y - mean) * rstd * r.y +
              (v.z - mean) * rstd * r.z + (v.w - mean) * rstd * r.w;
  dot = wave_sum(dot);
  __syncthreads();
  if ((t & 63) == 0) red[t >> 6] = dot;
  __syncthreads();
  if (t == 0) rowdot[row] = (red[0] + red[1]) + (red[2] + red[3]);
}

__global__ __launch_bounds__(256) void reduce_out(const float* __restrict__ rowdot,
                                                  float* __restrict__ out) {
  __shared__ float red[4];
  int b = blockIdx.x, t = threadIdx.x;
  float s = 0.f;
  for (int i = t; i < 2048; i += 256) s += rowdot[(size_t)b * 2048 + i];
  s = wave_sum(s);
  if ((t & 63) == 0) red[t >> 6] = s;
  __syncthreads();
  if (t == 0) out[b] = ((red[0] + red[1]) + (red[2] + red[3])) * (1.0f / 65536.0f);
}

extern "C" void kernel_launch(void* const* d_in, const int* in_sizes, int n_in,
                              void* d_out, int out_size, void* d_ws, size_t ws_size,
                              hipStream_t stream) {
  const float* seq     = (const float*)d_in[0];  // [8,2048,768]
  const float* emb     = (const float*)d_in[1];  // [768,1024]
  const float* W1      = (const float*)d_in[2];  // [1024,1024]
  const float* W2      = (const float*)d_in[3];  // [1024,1024]
  const float* readout = (const float*)d_in[4];  // [1024]
  float* out = (float*)d_out;                    // [8]

  char* ws = (char*)d_ws;
  const size_t MB = 1024u * 1024u;
  // aliased layout (verified rounds 3-12):
  unsigned short* x_b    = (unsigned short*)(ws + 0);        // 32MB [G1..LN1]
  unsigned short* h2b    = (unsigned short*)(ws + 0);        // 32MB [FFN2..LN2]
  unsigned short* xT     = (unsigned short*)(ws + 32 * MB);  // 32MB [gram_tr..attnV]
  unsigned short* hrelu  = (unsigned short*)(ws + 32 * MB);  // 32MB [FFN1..FFN2]
  unsigned short* gram   = (unsigned short*)(ws + 64 * MB);  // 64MB f16 [gram..sm]
  unsigned short* attn_b = (unsigned short*)(ws + 64 * MB);  // 32MB bf16 [aV..LN1]
  unsigned short* wts    = (unsigned short*)(ws + 128 * MB); // 64MB [sm..attnV]
  unsigned short* post_b = (unsigned short*)(ws + 128 * MB); // 32MB [LN1..LN2]
  unsigned short* embT   = (unsigned short*)(ws + 216 * MB);
  unsigned short* W1T    = (unsigned short*)(ws + 218 * MB);
  unsigned short* W2T    = (unsigned short*)(ws + 220 * MB);
  float*          rowdot = (float*)(ws + 222 * MB);

  // 1. all weight transposes, one launch
  transpose_cast3<<<dim3(32, 32, 3), dim3(32, 8), 0, stream>>>(emb, W1, W2,
                                                               embT, W1T, W2T);

  // 2. x = seq @ emb / sqrt(768) -> bf16 (fused f32 cast; grid 256)
  g1_fused<<<256, 512, 0, stream>>>(seq, embT, 0.03608439182435161f, x_b);

  // 3+4. gram (triangular, 576 blocks) + xT transpose (512 tail blocks)
  gram_tr<<<1088, 512, 0, stream>>>(x_b, gram, xT);

  // 5. weights = softmax(gram) -> bf16
  softmax_rows<<<16384, 256, 0, stream>>>(gram, wts);

  // 6. attn[b] = weights[b] @ x[b] -> bf16
  gemm_bt<<<256, 512, 0, stream>>>(wts, xT, 2048, 1024, 2048, 8,
                                   2048L * 2048, 1024L * 2048, 2048L * 1024,
                                   1.0f, EPI_BF, attn_b);

  // 7. post = LN(x + attn) -> bf16
  ln_residual_bb<<<16384, 256, 0, stream>>>(x_b, attn_b, post_b);

  // 8. FFN
  gemm_bt<<<256, 512, 0, stream>>>(post_b, W1T, 16384, 1024, 1024, 1, 0, 0, 0,
                                   0.03125f, EPI_RELUBF, hrelu);
  gemm_bt<<<256, 512, 0, stream>>>(hrelu, W2T, 16384, 1024, 1024, 1, 0, 0, 0,
                                   0.03125f, EPI_BF, h2b);

  // 9. final LN + pooled readout
  ln_residual_dot<<<16384, 256, 0, stream>>>(h2b, post_b, readout, rowdot);
  reduce_out<<<8, 256, 0, stream>>>(rowdot, out);
}

// Round 14
// 354.321 us; speedup vs baseline: 1.0506x; 1.0506x over previous
//
#include <hip/hip_runtime.h>
#include <hip/hip_bf16.h>

typedef __bf16 bf16x8 __attribute__((ext_vector_type(8)));
typedef float f32x4 __attribute__((ext_vector_type(4)));

__device__ __forceinline__ unsigned short f2bf(float f) {
  union { float f; unsigned u; } x; x.f = f;
  unsigned r = x.u + 0x7fffu + ((x.u >> 16) & 1u);
  return (unsigned short)(r >> 16);
}
__device__ __forceinline__ float bf2f(unsigned short u) {
  union { unsigned u; float f; } x; x.u = (unsigned)u << 16;
  return x.f;
}
__device__ __forceinline__ unsigned short f2h(float f) {
  union { _Float16 h; unsigned short u; } x; x.h = (_Float16)f;
  return x.u;
}
__device__ __forceinline__ float h2f(unsigned short u) {
  union { _Float16 h; unsigned short u; } x; x.u = u;
  return (float)x.h;
}

__device__ __forceinline__ void async_ld16(const void* g, void* l) {
  __builtin_amdgcn_global_load_lds(
      (__attribute__((address_space(1))) void*)const_cast<void*>(g),
      (__attribute__((address_space(3))) void*)l, 16, 0, 0);
}

#define SB __builtin_amdgcn_sched_barrier(0)

#define EPI_F32    0
#define EPI_BF     1
#define EPI_RELUBF 2
#define EPI_F16    3

// ---- r7 GEMM (best measured): 256x256, 4-phase K-split, 2 gates/K-tile ----
// Used for attnV + FFN1 + FFN2. Ledger/swizzle verified rounds 7-13.
__global__ __launch_bounds__(512, 2) void gemm_bt(
    const unsigned short* __restrict__ A,   // [nb][M][K] bf16
    const unsigned short* __restrict__ Bt,  // [nb][N][K] bf16
    int M, int N, int K, int nbatch,
    long sA, long sB, long sC,
    float scale, int mode, void* __restrict__ outp)
{
  __shared__ unsigned short lds[65536];  // 128 KB
  const int t = threadIdx.x;
  const int w = t >> 6, l = t & 63;
  const int lr = l & 15, lg = l >> 4;
  const int wr = w >> 2, wc = w & 3;           // 2 M-waves x 4 N-waves
  const int ntn = N >> 8;
  const int tiles = (M >> 8) * ntn;
  const int chunk = (tiles * nbatch) >> 3;
  const int bid = blockIdx.x;
  const int wg = (bid & 7) * chunk + (bid >> 3);
  const int batch = wg / tiles;
  const int rem = wg - batch * tiles;
  const int row0 = (rem / ntn) << 8;
  const int col0 = (rem % ntn) << 8;

  const unsigned short* Ab  = A  + (long)batch * sA;
  const unsigned short* Btb = Bt + (long)batch * sB;

  const int ks = ((lg ^ ((lr >> 1) & 3)) << 3);
  const int srow = w * 16 + (l >> 2);
  const int kgo  = (((l & 3) ^ ((l >> 3) & 3)) << 3);
  const long aoff0 = (long)(row0 + srow) * K + kgo;
  const long boff0 = (long)(col0 + srow) * K + kgo;
  const long off128 = (long)K << 7;

  const int NT = K >> 6;

#define STAGEP(partE, base, kcol)                                      \
  { async_ld16((base) + (kcol),          &lds[(partE) + t * 8]);       \
    async_ld16((base) + off128 + (kcol), &lds[(partE) + 4096 + t * 8]); }

  f32x4 acc[8][4];
#pragma unroll
  for (int m = 0; m < 8; ++m)
#pragma unroll
    for (int n = 0; n < 4; ++n) acc[m][n] = (f32x4){0.f, 0.f, 0.f, 0.f};

  STAGEP(0,     Btb + boff0, 0);
  STAGEP(8192,  Ab + aoff0,  0);
  STAGEP(16384, Btb + boff0, 32);
  STAGEP(24576, Ab + aoff0,  32);
  SB;

  for (int tt = 0; tt < NT; ++tt) {
    const int bufe  = (tt & 1) << 15;
    const int nbufe = ((tt + 1) & 1) << 15;
    const bool st = (tt + 1) < NT;
    const int kn = (tt + 1) << 6;

#pragma unroll
    for (int kh = 0; kh < 2; ++kh) {
      if (kh == 0 || st) { asm volatile("s_waitcnt vmcnt(4)" ::: "memory"); }
      else               { asm volatile("s_waitcnt vmcnt(0)" ::: "memory"); }
      SB;
      __builtin_amdgcn_s_barrier();
      SB;

      const int pB = bufe + kh * 16384;
      const int pA = pB + 8192;

      bf16x8 bfr[4];
#pragma unroll
      for (int nf = 0; nf < 4; ++nf) {
        int rb = wc * 64 + nf * 16 + lr;
        bfr[nf] = *(const bf16x8*)&lds[pB + rb * 32 + ks];
      }
      {
        bf16x8 af[4];
#pragma unroll
        for (int i = 0; i < 4; ++i) {
          int ra = wr * 128 + i * 16 + lr;
          af[i] = *(const bf16x8*)&lds[pA + ra * 32 + ks];
        }
        if (st) STAGEP(nbufe + kh * 16384, Btb + boff0, kn + kh * 32);
        __builtin_amdgcn_s_setprio(1);
#pragma unroll
        for (int i = 0; i < 4; ++i)
#pragma unroll
          for (int nf = 0; nf < 4; ++nf)
            acc[i][nf] = __builtin_amdgcn_mfma_f32_16x16x32_bf16(af[i], bfr[nf], acc[i][nf], 0, 0, 0);
        __builtin_amdgcn_s_setprio(0);
      }
      {
        bf16x8 af[4];
#pragma unroll
        for (int i = 0; i < 4; ++i) {
          int ra = wr * 128 + 64 + i * 16 + lr;
          af[i] = *(const bf16x8*)&lds[pA + ra * 32 + ks];
        }
        if (st) STAGEP(nbufe + kh * 16384 + 8192, Ab + aoff0, kn + kh * 32);
        __builtin_amdgcn_s_setprio(1);
#pragma unroll
        for (int i = 0; i < 4; ++i)
#pragma unroll
          for (int nf = 0; nf < 4; ++nf)
            acc[4 + i][nf] = __builtin_amdgcn_mfma_f32_16x16x32_bf16(af[i], bfr[nf], acc[4 + i][nf], 0, 0, 0);
        __builtin_amdgcn_s_setprio(0);
      }
      SB;
    }
  }

  float* outF = (float*)outp;
  unsigned short* outH = (unsigned short*)outp;
  const size_t cb = (size_t)batch * (size_t)sC;
#pragma unroll
  for (int mf = 0; mf < 8; ++mf) {
    int rbase = row0 + wr * 128 + mf * 16 + lg * 4;
#pragma unroll
    for (int nf = 0; nf < 4; ++nf) {
      int c = col0 + wc * 64 + nf * 16 + lr;
      f32x4 v = acc[mf][nf];
#pragma unroll
      for (int q = 0; q < 4; ++q) {
        size_t idx = cb + (size_t)(rbase + q) * N + c;
        float val = v[q] * scale;
        if (mode == EPI_F32)         outF[idx] = val;
        else if (mode == EPI_BF)     outH[idx] = f2bf(val);
        else if (mode == EPI_RELUBF) outH[idx] = f2bf(fmaxf(val, 0.f));
        else                         outH[idx] = f2h(val);
      }
    }
  }
#undef STAGEP
}

// ---- g1_fused: x = seq(f32) @ embT^T * scale -> bf16 (r11 version) ----
__global__ __launch_bounds__(512, 2) void g1_fused(
    const float* __restrict__ A,            // [16384][768] f32
    const unsigned short* __restrict__ Bt,  // [1024][768] bf16
    float scale, unsigned short* __restrict__ outB)
{
  __shared__ unsigned short lds[65536];
  const int t = threadIdx.x;
  const int w = t >> 6, l = t & 63;
  const int lr = l & 15, lg = l >> 4;
  const int wr = w >> 2, wc = w & 3;
  const int K = 768;
  const int bid = blockIdx.x;
  const int wg = (bid & 7) * 32 + (bid >> 3);   // 256 tiles (64x4)
  const int row0 = (wg >> 2) << 8;
  const int col0 = (wg & 3) << 8;

  const int ks = ((lg ^ ((lr >> 1) & 3)) << 3);
  const int srow = w * 16 + (l >> 2);
  const int kgo  = (((l & 3) ^ ((l >> 3) & 3)) << 3);
  const long ar0 = (long)(row0 + srow) * K + kgo;
  const long ar1 = ar0 + (long)128 * K;
  const long boff0 = (long)(col0 + srow) * K + kgo;
  const long off128 = (long)K << 7;
  const int NT = 12;

#define STAGEB(partE, kcol)                                              \
  { async_ld16(Bt + boff0 + (kcol),          &lds[(partE) + t * 8]);     \
    async_ld16(Bt + boff0 + off128 + (kcol), &lds[(partE) + 4096 + t * 8]); }
#define WRA(partE, q0, q1, q2, q3)                                       \
  { uint4 pk;                                                            \
    pk.x = (unsigned)f2bf(q0.x) | ((unsigned)f2bf(q0.y) << 16);          \
    pk.y = (unsigned)f2bf(q0.z) | ((unsigned)f2bf(q0.w) << 16);          \
    pk.z = (unsigned)f2bf(q1.x) | ((unsigned)f2bf(q1.y) << 16);          \
    pk.w = (unsigned)f2bf(q1.z) | ((unsigned)f2bf(q1.w) << 16);          \
    *(uint4*)&lds[(partE) + t * 8] = pk;                                 \
    pk.x = (unsigned)f2bf(q2.x) | ((unsigned)f2bf(q2.y) << 16);          \
    pk.y = (unsigned)f2bf(q2.z) | ((unsigned)f2bf(q2.w) << 16);          \
    pk.z = (unsigned)f2bf(q3.x) | ((unsigned)f2bf(q3.y) << 16);          \
    pk.w = (unsigned)f2bf(q3.z) | ((unsigned)f2bf(q3.w) << 16);          \
    *(uint4*)&lds[(partE) + 4096 + t * 8] = pk; }

  f32x4 acc[8][4];
#pragma unroll
  for (int m = 0; m < 8; ++m)
#pragma unroll
    for (int n = 0; n < 4; ++n) acc[m][n] = (f32x4){0.f, 0.f, 0.f, 0.f};

  float4 ap0, ap1, ap2, ap3, ap4, ap5, ap6, ap7;
  ap0 = *(const float4*)&A[ar0];      ap1 = *(const float4*)&A[ar0 + 4];
  ap2 = *(const float4*)&A[ar1];      ap3 = *(const float4*)&A[ar1 + 4];
  ap4 = *(const float4*)&A[ar0 + 32]; ap5 = *(const float4*)&A[ar0 + 36];
  ap6 = *(const float4*)&A[ar1 + 32]; ap7 = *(const float4*)&A[ar1 + 36];
  STAGEB(0, 0);
  STAGEB(16384, 32);
  WRA(8192,  ap0, ap1, ap2, ap3);
  WRA(24576, ap4, ap5, ap6, ap7);
  SB;

  for (int tt = 0; tt < NT; ++tt) {
    const int bufe  = (tt & 1) << 15;
    const int nbufe = ((tt + 1) & 1) << 15;
    const bool st = (tt + 1) < NT;
    const int kn = (tt + 1) << 6;

#pragma unroll
    for (int kh = 0; kh < 2; ++kh) {
      if (kh == 0)  { asm volatile("s_waitcnt vmcnt(2) lgkmcnt(0)" ::: "memory"); }
      else if (st)  { asm volatile("s_waitcnt vmcnt(10) lgkmcnt(0)" ::: "memory"); }
      else          { asm volatile("s_waitcnt vmcnt(0) lgkmcnt(0)" ::: "memory"); }
      SB;
      __builtin_amdgcn_s_barrier();
      SB;

      const int pB = bufe + kh * 16384;
      const int pA = pB + 8192;

      bf16x8 bfr[4];
#pragma unroll
      for (int nf = 0; nf < 4; ++nf) {
        int rb = wc * 64 + nf * 16 + lr;
        bfr[nf] = *(const bf16x8*)&lds[pB + rb * 32 + ks];
      }
      {
        bf16x8 af[4];
#pragma unroll
        for (int i = 0; i < 4; ++i) {
          int ra = wr * 128 + i * 16 + lr;
          af[i] = *(const bf16x8*)&lds[pA + ra * 32 + ks];
        }
        if (kh == 0 && st) {
          ap0 = *(const float4*)&A[ar0 + kn];      ap1 = *(const float4*)&A[ar0 + kn + 4];
          ap2 = *(const float4*)&A[ar1 + kn];      ap3 = *(const float4*)&A[ar1 + kn + 4];
          ap4 = *(const float4*)&A[ar0 + kn + 32]; ap5 = *(const float4*)&A[ar0 + kn + 36];
          ap6 = *(const float4*)&A[ar1 + kn + 32]; ap7 = *(const float4*)&A[ar1 + kn + 36];
          STAGEB(nbufe + 0, kn);
        }
        __builtin_amdgcn_s_setprio(1);
#pragma unroll
        for (int i = 0; i < 4; ++i)
#pragma unroll
          for (int nf = 0; nf < 4; ++nf)
            acc[i][nf] = __builtin_amdgcn_mfma_f32_16x16x32_bf16(af[i], bfr[nf], acc[i][nf], 0, 0, 0);
        __builtin_amdgcn_s_setprio(0);
      }
      {
        bf16x8 af[4];
#pragma unroll
        for (int i = 0; i < 4; ++i) {
          int ra = wr * 128 + 64 + i * 16 + lr;
          af[i] = *(const bf16x8*)&lds[pA + ra * 32 + ks];
        }
        if (kh == 1 && st) STAGEB(nbufe + 16384, kn + 32);
        __builtin_amdgcn_s_setprio(1);
#pragma unroll
        for (int i = 0; i < 4; ++i)
#pragma unroll
          for (int nf = 0; nf < 4; ++nf)
            acc[4 + i][nf] = __builtin_amdgcn_mfma_f32_16x16x32_bf16(af[i], bfr[nf], acc[4 + i][nf], 0, 0, 0);
        __builtin_amdgcn_s_setprio(0);
        if (kh == 1 && st) {
          WRA(nbufe + 8192,  ap0, ap1, ap2, ap3);
          WRA(nbufe + 24576, ap4, ap5, ap6, ap7);
        }
      }
      SB;
    }
  }

#pragma unroll
  for (int mf = 0; mf < 8; ++mf) {
    int rbase = row0 + wr * 128 + mf * 16 + lg * 4;
#pragma unroll
    for (int nf = 0; nf < 4; ++nf) {
      int c = col0 + wc * 64 + nf * 16 + lr;
      f32x4 v = acc[mf][nf];
#pragma unroll
      for (int q = 0; q < 4; ++q)
        outB[(size_t)(rbase + q) * 1024 + c] = f2bf(v[q] * scale);
    }
  }
#undef STAGEB
#undef WRA
}

// ---- gram_sym2: triangular 128x256 gram -> f16 (r11 version) ----
__global__ __launch_bounds__(512, 2) void gram_sym2(
    const unsigned short* __restrict__ X,   // [8][2048][1024] bf16
    unsigned short* __restrict__ outH)      // [8][2048][2048] f16
{
  __shared__ unsigned short lds[49152];  // 96 KB
  const int t = threadIdx.x;
  const int w = t >> 6, l = t & 63;
  const int lr = l & 15, lg = l >> 4;
  const int wr = w >> 2, wc = w & 3;     // 2 M-waves x 4 N-waves
  const int bid = blockIdx.x;
  const int wg = (bid & 7) * 72 + (bid >> 3);
  const int batch = wg / 72;
  int f = wg - batch * 72;
  int bi = 0;
  while (f >= 8 - (bi >> 1)) { f -= 8 - (bi >> 1); ++bi; }
  const int bj = (bi >> 1) + f;
  const int row0 = bi << 7;              // 128-row tile
  const int col0 = bj << 8;              // 256-col tile

  const unsigned short* Xb = X + (long)batch * 2048 * 1024;

  const int ks = ((lg ^ ((lr >> 1) & 3)) << 3);
  const int srow = w * 16 + (l >> 2);
  const int kgoB = (((l & 3) ^ ((l >> 3) & 3)) << 3);
  const long boff0 = (long)(col0 + srow) * 1024 + kgoB;
  const long off128 = 1024L << 7;
  const long arow = (long)(row0 + (t >> 2)) * 1024 + (((t & 3) ^ ((t >> 3) & 3)) << 3);

#define STAGEB2(partE, kcol)                                              \
  { async_ld16(Xb + boff0 + (kcol),          &lds[(partE) + t * 8]);      \
    async_ld16(Xb + boff0 + off128 + (kcol), &lds[(partE) + 4096 + t * 8]); }
#define STAGEA2(partE, kcol)                                              \
  { async_ld16(Xb + arow + (kcol), &lds[(partE) + t * 8]); }

  f32x4 acc[4][4];
#pragma unroll
  for (int m = 0; m < 4; ++m)
#pragma unroll
    for (int n = 0; n < 4; ++n) acc[m][n] = (f32x4){0.f, 0.f, 0.f, 0.f};

  STAGEB2(0, 0);
  STAGEA2(8192, 0);
  STAGEB2(12288, 32);
  STAGEA2(20480, 32);
  SB;

  for (int tt = 0; tt < 16; ++tt) {
    const int bufe  = (tt & 1) * 24576;
    const int nbufe = ((tt + 1) & 1) * 24576;
    const bool st = (tt + 1) < 16;
    const int kn = (tt + 1) << 6;

#pragma unroll
    for (int kh = 0; kh < 2; ++kh) {
      if (kh == 0 || st) { asm volatile("s_waitcnt vmcnt(3)" ::: "memory"); }
      else               { asm volatile("s_waitcnt vmcnt(0)" ::: "memory"); }
      SB;
      __builtin_amdgcn_s_barrier();
      SB;

      const int pB = bufe + kh * 12288;
      const int pA = pB + 8192;

      bf16x8 bfr[4];
#pragma unroll
      for (int nf = 0; nf < 4; ++nf) {
        int rb = wc * 64 + nf * 16 + lr;
        bfr[nf] = *(const bf16x8*)&lds[pB + rb * 32 + ks];
      }
#pragma unroll
      for (int mh = 0; mh < 2; ++mh) {
        bf16x8 af[2];
#pragma unroll
        for (int i = 0; i < 2; ++i) {
          int ra = wr * 64 + mh * 32 + i * 16 + lr;
          af[i] = *(const bf16x8*)&lds[pA + ra * 32 + ks];
        }
        if (st) {
          if (mh == 0) { if (kh == 0) STAGEB2(nbufe + 0, kn) else STAGEB2(nbufe + 12288, kn + 32) }
          else         { if (kh == 0) STAGEA2(nbufe + 8192, kn) else STAGEA2(nbufe + 20480, kn + 32) }
        }
        __builtin_amdgcn_s_setprio(1);
#pragma unroll
        for (int i = 0; i < 2; ++i)
#pragma unroll
          for (int nf = 0; nf < 4; ++nf)
            acc[mh * 2 + i][nf] = __builtin_amdgcn_mfma_f32_16x16x32_bf16(af[i], bfr[nf], acc[mh * 2 + i][nf], 0, 0, 0);
        __builtin_amdgcn_s_setprio(0);
      }
      SB;
    }
  }

  unsigned short* ob = outH + (size_t)batch * 2048 * 2048;
  const float scale = 1.0f / 1024.0f;
#pragma unroll
  for (int am = 0; am < 4; ++am) {
    int rbase = row0 + wr * 64 + (am >> 1) * 32 + (am & 1) * 16 + lg * 4;
#pragma unroll
    for (int nf = 0; nf < 4; ++nf) {
      int c = col0 + wc * 64 + nf * 16 + lr;
      f32x4 v = acc[am][nf];
      unsigned short h0 = f2h(v[0] * scale), h1 = f2h(v[1] * scale);
      unsigned short h2 = f2h(v[2] * scale), h3 = f2h(v[3] * scale);
      ob[(size_t)(rbase + 0) * 2048 + c] = h0;
      ob[(size_t)(rbase + 1) * 2048 + c] = h1;
      ob[(size_t)(rbase + 2) * 2048 + c] = h2;
      ob[(size_t)(rbase + 3) * 2048 + c] = h3;
      ushort4 m4 = {h0, h1, h2, h3};
      *(ushort4*)&ob[(size_t)c * 2048 + rbase] = m4;
    }
  }
#undef STAGEB2
#undef STAGEA2
}

// ---------------- elementwise / reduction kernels ----------------

__device__ __forceinline__ float wave_sum(float v) {
#pragma unroll
  for (int o = 32; o; o >>= 1) v += __shfl_xor(v, o, 64);
  return v;
}
__device__ __forceinline__ float wave_max(float v) {
#pragma unroll
  for (int o = 32; o; o >>= 1) v = fmaxf(v, __shfl_xor(v, o, 64));
  return v;
}

// all three weight transposes in one launch: z=0 emb[768][1024], z=1 W1, z=2 W2
__global__ __launch_bounds__(256) void transpose_cast3(
    const float* __restrict__ emb, const float* __restrict__ W1,
    const float* __restrict__ W2, unsigned short* __restrict__ embT,
    unsigned short* __restrict__ W1T, unsigned short* __restrict__ W2T) {
  __shared__ float tile[32][33];
  const int z = blockIdx.z;
  const float* in = (z == 0) ? emb : (z == 1) ? W1 : W2;
  unsigned short* out = (z == 0) ? embT : (z == 1) ? W1T : W2T;
  const int R = (z == 0) ? 768 : 1024;
  int c0 = blockIdx.x * 32, r0 = blockIdx.y * 32;
  if (r0 >= R) return;
  int tx = threadIdx.x, ty = threadIdx.y;  // block (32,8)
  for (int i = ty; i < 32; i += 8) tile[i][tx] = in[(size_t)(r0 + i) * 1024 + c0 + tx];
  __syncthreads();
  for (int i = ty; i < 32; i += 8) out[(size_t)(c0 + i) * R + r0 + tx] = f2bf(tile[tx][i]);
}

// per-batch bf16 transpose: in[z][R][C] -> out[z][C][R]
__global__ __launch_bounds__(256) void transpose_b16(const unsigned short* __restrict__ in,
                                                     unsigned short* __restrict__ out,
                                                     int R, int C) {
  __shared__ unsigned short tile[32][33];
  int c0 = blockIdx.x * 32, r0 = blockIdx.y * 32;
  size_t zb = (size_t)blockIdx.z * R * C;
  int tx = threadIdx.x, ty = threadIdx.y;  // block (32,8)
  for (int i = ty; i < 32; i += 8) tile[i][tx] = in[zb + (size_t)(r0 + i) * C + c0 + tx];
  __syncthreads();
  for (int i = ty; i < 32; i += 8) out[zb + (size_t)(c0 + i) * R + r0 + tx] = tile[tx][i];
}

__global__ __launch_bounds__(256) void softmax_rows(const unsigned short* __restrict__ g,
                                                    unsigned short* __restrict__ wout) {
  __shared__ float red[4];
  int row = blockIdx.x, t = threadIdx.x;
  const unsigned short* gr = g + ((size_t)row << 11) + t * 8;
  ushort4 ua = *(const ushort4*)gr;
  ushort4 ub = *(const ushort4*)(gr + 4);
  float a0 = h2f(ua.x), a1 = h2f(ua.y), a2 = h2f(ua.z), a3 = h2f(ua.w);
  float b0 = h2f(ub.x), b1 = h2f(ub.y), b2 = h2f(ub.z), b3 = h2f(ub.w);
  float mx = fmaxf(fmaxf(fmaxf(a0, a1), fmaxf(a2, a3)),
                   fmaxf(fmaxf(b0, b1), fmaxf(b2, b3)));
  mx = wave_max(mx);
  if ((t & 63) == 0) red[t >> 6] = mx;
  __syncthreads();
  mx = fmaxf(fmaxf(red[0], red[1]), fmaxf(red[2], red[3]));
  float e0 = __expf(a0 - mx), e1 = __expf(a1 - mx), e2 = __expf(a2 - mx), e3 = __expf(a3 - mx);
  float e4 = __expf(b0 - mx), e5 = __expf(b1 - mx), e6 = __expf(b2 - mx), e7 = __expf(b3 - mx);
  float s = ((e0 + e1) + (e2 + e3)) + ((e4 + e5) + (e6 + e7));
  s = wave_sum(s);
  __syncthreads();
  if ((t & 63) == 0) red[t >> 6] = s;
  __syncthreads();
  s = (red[0] + red[1]) + (red[2] + red[3]);
  float inv = 1.0f / s;
  ushort4 o0, o1;
  o0.x = f2bf(e0 * inv); o0.y = f2bf(e1 * inv); o0.z = f2bf(e2 * inv); o0.w = f2bf(e3 * inv);
  o1.x = f2bf(e4 * inv); o1.y = f2bf(e5 * inv); o1.z = f2bf(e6 * inv); o1.w = f2bf(e7 * inv);
  size_t base = ((size_t)row << 11) + t * 8;
  *(ushort4*)&wout[base] = o0;
  *(ushort4*)&wout[base + 4] = o1;
}

// post = LN(x_b + attn_b), both bf16
__global__ __launch_bounds__(256) void ln_residual_bb(const unsigned short* __restrict__ xb,
                                                      const unsigned short* __restrict__ ab,
                                                      unsigned short* __restrict__ outB) {
  __shared__ float red[4];
  int row = blockIdx.x, t = threadIdx.x;
  size_t base = ((size_t)row << 10) + t * 4;
  ushort4 ua = *(const ushort4*)&xb[base];
  ushort4 ub = *(const ushort4*)&ab[base];
  float4 v = {bf2f(ua.x) + bf2f(ub.x), bf2f(ua.y) + bf2f(ub.y),
              bf2f(ua.z) + bf2f(ub.z), bf2f(ua.w) + bf2f(ub.w)};
  float s = (v.x + v.y) + (v.z + v.w);
  float ss = (v.x * v.x + v.y * v.y) + (v.z * v.z + v.w * v.w);
  s = wave_sum(s);
  if ((t & 63) == 0) red[t >> 6] = s;
  __syncthreads();
  s = (red[0] + red[1]) + (red[2] + red[3]);
  ss = wave_sum(ss);
  __syncthreads();
  if ((t & 63) == 0) red[t >> 6] = ss;
  __syncthreads();
  ss = (red[0] + red[1]) + (red[2] + red[3]);
  float mean = s * (1.0f / 1024.0f);
  float var = (ss - s * mean) * (1.0f / 1023.0f);
  float rstd = rsqrtf(var);
  ushort4 ob;
  ob.x = f2bf((v.x - mean) * rstd); ob.y = f2bf((v.y - mean) * rstd);
  ob.z = f2bf((v.z - mean) * rstd); ob.w = f2bf((v.w - mean) * rstd);
  *(ushort4*)&outB[base] = ob;
}

__global__ __launch_bounds__(256) void ln_residual_dot(const unsigned short* __restrict__ h2,
                                                       const unsigned short* __restrict__ post,
                                                       const float* __restrict__ readout,
                                                       float* __restrict__ rowdot) {
  __shared__ float red[4];
  int row = blockIdx.x, t = threadIdx.x;
  size_t base = ((size_t)row << 10) + t * 4;
  ushort4 ua = *(const ushort4*)&h2[base];
  ushort4 ub = *(const ushort4*)&post[base];
  float4 v = {bf2f(ua.x) + bf2f(ub.x), bf2f(ua.y) + bf2f(ub.y),
              bf2f(ua.z) + bf2f(ub.z), bf2f(ua.w) + bf2f(ub.w)};
  float s = (v.x + v.y) + (v.z + v.w);
  float ss = (v.x * v.x + v.y * v.y) + (v.z * v.z + v.w * v.w);
  s = wave_sum(s);
  if ((t & 63) == 0) red[t >> 6] = s;
  __syncthreads();
  s = (red[0] + red[1]) + (red[2] + red[3]);
  ss = wave_sum(ss);
  __syncthreads();
  if ((t & 63) == 0) red[t >> 6] = ss;
  __syncthreads();
  ss = (red[0] + red[1]) + (red[2] + red[3]);
  float mean = s * (1.0f / 1024.0f);
  float var = (ss - s * mean) * (1.0f / 1023.0f);
  float rstd = rsqrtf(var);
  float4 r = *(const float4*)&readout[t * 4];
  float dot = (v.x - mean) * rstd * r.x + (v.y - mean) * rstd * r.y +
              (v.z - mean) * rstd * r.z + (v.w - mean) * rstd * r.w;
  dot = wave_sum(dot);
  __syncthreads();
  if ((t & 63) == 0) red[t >> 6] = dot;
  __syncthreads();
  if (t == 0) rowdot[row] = (red[0] + red[1]) + (red[2] + red[3]);
}

__global__ __launch_bounds__(256) void reduce_out(const float* __restrict__ rowdot,
                                                  float* __restrict__ out) {
  __shared__ float red[4];
  int b = blockIdx.x, t = threadIdx.x;
  float s = 0.f;
  for (int i = t; i < 2048; i += 256) s += rowdot[(size_t)b * 2048 + i];
  s = wave_sum(s);
  if ((t & 63) == 0) red[t >> 6] = s;
  __syncthreads();
  if (t == 0) out[b] = ((red[0] + red[1]) + (red[2] + red[3])) * (1.0f / 65536.0f);
}

extern "C" void kernel_launch(void* const* d_in, const int* in_sizes, int n_in,
                              void* d_out, int out_size, void* d_ws, size_t ws_size,
                              hipStream_t stream) {
  const float* seq     = (const float*)d_in[0];  // [8,2048,768]
  const float* emb     = (const float*)d_in[1];  // [768,1024]
  const float* W1      = (const float*)d_in[2];  // [1024,1024]
  const float* W2      = (const float*)d_in[3];  // [1024,1024]
  const float* readout = (const float*)d_in[4];  // [1024]
  float* out = (float*)d_out;                    // [8]

  char* ws = (char*)d_ws;
  const size_t MB = 1024u * 1024u;
  // aliased layout (verified rounds 3-13):
  unsigned short* x_b    = (unsigned short*)(ws + 0);        // 32MB [G1..LN1]
  unsigned short* h2b    = (unsigned short*)(ws + 0);        // 32MB [FFN2..LN2]
  unsigned short* xT     = (unsigned short*)(ws + 32 * MB);  // 32MB [tr..attnV]
  unsigned short* hrelu  = (unsigned short*)(ws + 32 * MB);  // 32MB [FFN1..FFN2]
  unsigned short* gram   = (unsigned short*)(ws + 64 * MB);  // 64MB f16 [gram..sm]
  unsigned short* attn_b = (unsigned short*)(ws + 64 * MB);  // 32MB bf16 [aV..LN1]
  unsigned short* wts    = (unsigned short*)(ws + 128 * MB); // 64MB [sm..attnV]
  unsigned short* post_b = (unsigned short*)(ws + 128 * MB); // 32MB [LN1..LN2]
  unsigned short* embT   = (unsigned short*)(ws + 216 * MB);
  unsigned short* W1T    = (unsigned short*)(ws + 218 * MB);
  unsigned short* W2T    = (unsigned short*)(ws + 220 * MB);
  float*          rowdot = (float*)(ws + 222 * MB);

  // 1. all weight transposes, one launch
  transpose_cast3<<<dim3(32, 32, 3), dim3(32, 8), 0, stream>>>(emb, W1, W2,
                                                               embT, W1T, W2T);

  // 2. x = seq @ emb / sqrt(768) -> bf16 (fused f32 cast; grid 256)
  g1_fused<<<256, 512, 0, stream>>>(seq, embT, 0.03608439182435161f, x_b);

  // 3. xT[b] = x[b]^T
  transpose_b16<<<dim3(32, 64, 8), dim3(32, 8), 0, stream>>>(x_b, xT, 2048, 1024);

  // 4. gram[b] = x[b] @ x[b]^T / 1024 -> f16, triangular 128x256 tiles
  gram_sym2<<<576, 512, 0, stream>>>(x_b, gram);

  // 5. weights = softmax(gram) -> bf16
  softmax_rows<<<16384, 256, 0, stream>>>(gram, wts);

  // 6. attn[b] = weights[b] @ x[b] -> bf16
  gemm_bt<<<256, 512, 0, stream>>>(wts, xT, 2048, 1024, 2048, 8,
                                   2048L * 2048, 1024L * 2048, 2048L * 1024,
                                   1.0f, EPI_BF, attn_b);

  // 7. post = LN(x + attn) -> bf16
  ln_residual_bb<<<16384, 256, 0, stream>>>(x_b, attn_b, post_b);

  // 8. FFN
  gemm_bt<<<256, 512, 0, stream>>>(post_b, W1T, 16384, 1024, 1024, 1, 0, 0, 0,
                                   0.03125f, EPI_RELUBF, hrelu);
  gemm_bt<<<256, 512, 0, stream>>>(hrelu, W2T, 16384, 1024, 1024, 1, 0, 0, 0,
                                   0.03125f, EPI_BF, h2b);

  // 9. final LN + pooled readout
  ln_residual_dot<<<16384, 256, 0, stream>>>(h2b, post_b, readout, rowdot);
  reduce_out<<<8, 256, 0, stream>>>(rowdot, out);
}